// Round 2
// baseline (505.688 us; speedup 1.0000x reference)
//
#include <hip/hip_runtime.h>

// SKA: out[n,c,y,x] = sum_{i,j} x_pad[n,c,y+i,x+j] * w[n, c%8, i*7+j, y, x]
// n=8, ic=512, h=w=96, wc=8, ks=7, pad=3. fp32 in/out.
//
// Block = (ytile, cw, n): 384 threads = 24 x-slots (float4 each) x 16 g-slots.
// Each thread computes 4 channels (g = gi*16 + g_slot) x 4 pixels per y-row.
// w row (49 taps x 96 cols, 18.4 KB) staged in LDS, double-buffered with
// register prefetch one row ahead; one barrier per y-row.

typedef float f4 __attribute__((ext_vector_type(4)));  // native vec: OK for
                                                       // __builtin_nontemporal_*

#define N_      8
#define IC_     512
#define H_      96
#define W_      96
#define WC_     8
#define KS_     7
#define NG_     4
#define GSLOTS_ 16
#define XSLOTS_ 24
#define YC_     12
#define NTHR_   (XSLOTS_ * GSLOTS_)        // 384
#define WROW_F4_ (KS_ * KS_ * XSLOTS_)     // 1176 f4 per staged w row

__global__ __launch_bounds__(NTHR_, 3)
void ska_kernel(const float* __restrict__ x, const float* __restrict__ w,
                float* __restrict__ out) {
    __shared__ f4 wlds[2][WROW_F4_];       // 2 x 18816 B

    const int tid    = threadIdx.x;
    const int ytile  = blockIdx.x;
    const int cw     = blockIdx.y;
    const int n      = blockIdx.z;
    const int y0     = ytile * YC_;

    const int x_slot = tid % XSLOTS_;      // 0..23
    const int g_slot = tid / XSLOTS_;      // 0..15
    const int xq     = x_slot * 4;         // output col base

    // w as f4: index (tap*H + y)*24 + x_slot within the (n,cw) plane
    const f4* wg = reinterpret_cast<const f4*>(w)
                 + (size_t)((n * WC_ + cw) * (KS_ * KS_)) * (H_ * W_ / 4);

    // per-gi channel plane offsets (c = (gi*16 + g_slot)*8 + cw)
    int xoff[NG_], ooff[NG_];
#pragma unroll
    for (int gi = 0; gi < NG_; ++gi) {
        const int c     = (gi * GSLOTS_ + g_slot) * WC_ + cw;
        const int plane = (n * IC_ + c) * (H_ * W_);
        xoff[gi] = plane + xq - 4;   // window starts at col xq-4
        ooff[gi] = plane + xq;
    }

    f4 pre[4];

    // ---- stage w row y0 into buffer 0 ----
    {
#pragma unroll
        for (int k = 0; k < 4; ++k) {
            const int tap = g_slot + GSLOTS_ * k;          // f = tid + 384k
            if (k < 3 || g_slot == 0) {                    // tap < 49
                pre[k] = __builtin_nontemporal_load(
                    &wg[(tap * H_ + y0) * XSLOTS_ + x_slot]);
            }
        }
#pragma unroll
        for (int k = 0; k < 4; ++k) {
            const int tap = g_slot + GSLOTS_ * k;
            if (k < 3 || g_slot == 0)
                wlds[0][tap * XSLOTS_ + x_slot] = pre[k];
        }
    }
    __syncthreads();

    for (int yt = 0; yt < YC_; ++yt) {
        const int y = y0 + yt;
        const bool havenext = (yt + 1 < YC_);

        // issue next-row w prefetch early (lands during compute)
        if (havenext) {
            const int yn = y + 1;
#pragma unroll
            for (int k = 0; k < 4; ++k) {
                const int tap = g_slot + GSLOTS_ * k;
                if (k < 3 || g_slot == 0) {
                    pre[k] = __builtin_nontemporal_load(
                        &wg[(tap * H_ + yn) * XSLOTS_ + x_slot]);
                }
            }
        }

        const f4* wl = wlds[yt & 1];

        float acc[NG_][4];
#pragma unroll
        for (int gi = 0; gi < NG_; ++gi)
#pragma unroll
            for (int k = 0; k < 4; ++k) acc[gi][k] = 0.f;

#pragma unroll
        for (int i = 0; i < KS_; ++i) {
            const int ry = y + i - 3;
            if (ry >= 0 && ry < H_) {                      // block-uniform
                const int rbase = ry * W_;
                float win[NG_][12];
#pragma unroll
                for (int gi = 0; gi < NG_; ++gi) {
                    const float* rowp = x + xoff[gi] + rbase;
                    f4 A = (f4)0.f;
                    f4 C = (f4)0.f;
                    if (x_slot != 0)
                        A = *reinterpret_cast<const f4*>(rowp);
                    const f4 B = *reinterpret_cast<const f4*>(rowp + 4);
                    if (x_slot != XSLOTS_ - 1)
                        C = *reinterpret_cast<const f4*>(rowp + 8);
                    win[gi][0] = A.x;  win[gi][1] = A.y;
                    win[gi][2] = A.z;  win[gi][3] = A.w;
                    win[gi][4] = B.x;  win[gi][5] = B.y;
                    win[gi][6] = B.z;  win[gi][7] = B.w;
                    win[gi][8] = C.x;  win[gi][9] = C.y;
                    win[gi][10] = C.z; win[gi][11] = C.w;
                }
#pragma unroll
                for (int j = 0; j < KS_; ++j) {
                    const f4 w4 = wl[(i * KS_ + j) * XSLOTS_ + x_slot];
                    const float wv[4] = {w4.x, w4.y, w4.z, w4.w};
#pragma unroll
                    for (int gi = 0; gi < NG_; ++gi)
#pragma unroll
                        for (int k = 0; k < 4; ++k)
                            acc[gi][k] = __builtin_fmaf(win[gi][1 + j + k],
                                                        wv[k], acc[gi][k]);
                }
            }
        }

        // store 4 channels x f4, written exactly once -> nontemporal
#pragma unroll
        for (int gi = 0; gi < NG_; ++gi) {
            f4 o;
            o.x = acc[gi][0]; o.y = acc[gi][1];
            o.z = acc[gi][2]; o.w = acc[gi][3];
            __builtin_nontemporal_store(
                o, reinterpret_cast<f4*>(out + ooff[gi] + y * W_));
        }

        // commit prefetched w row into the other buffer; one barrier/row
        if (havenext) {
#pragma unroll
            for (int k = 0; k < 4; ++k) {
                const int tap = g_slot + GSLOTS_ * k;
                if (k < 3 || g_slot == 0)
                    wlds[(yt + 1) & 1][tap * XSLOTS_ + x_slot] = pre[k];
            }
        }
        __syncthreads();
    }
}

extern "C" void kernel_launch(void* const* d_in, const int* in_sizes, int n_in,
                              void* d_out, int out_size, void* d_ws, size_t ws_size,
                              hipStream_t stream) {
    const float* x = reinterpret_cast<const float*>(d_in[0]);
    const float* w = reinterpret_cast<const float*>(d_in[1]);
    float* out     = reinterpret_cast<float*>(d_out);

    dim3 grid(H_ / YC_, WC_, N_);   // (8, 8, 8) = 512 blocks
    dim3 block(NTHR_);              // 384 threads
    hipLaunchKernelGGL(ska_kernel, grid, block, 0, stream, x, w, out);
}